// Round 11
// baseline (694.719 us; speedup 1.0000x reference)
//
#include <hip/hip_runtime.h>
#include <cstdint>
#include <cstddef>

#define N_ROWS   65536
#define D_IN     512
#define D_OUT    512
#define N_WORDS  256
#define N_BOOKS  8
#define TAU      5.0f
#define LOG2E    1.44269504088896340736f

typedef __attribute__((ext_vector_type(8))) short short8;
typedef __attribute__((ext_vector_type(4))) float f32x4;

// hardware bf16 convert (RNE) — native __bf16 lets the compiler pair into v_cvt_pk_bf16_f32
__device__ __forceinline__ unsigned short f2bf(float f) {
    __bf16 h = (__bf16)f;
    return __builtin_bit_cast(unsigned short, h);
}
__device__ __forceinline__ float bf2f(unsigned short h) {
    unsigned u = ((unsigned)h) << 16;
    return __builtin_bit_cast(float, u);
}

// ============ Kernel 0: pre-pack codebook + W into MFMA fragment order ============
// packA [b][ks(2)][mf(16)][lane(64)][i(8)] : A-frag for xc GEMM (row=m, k=feature)
// packB [b][ks2(8)][n2(4)][lane(64)][i(8)] : B-frag for Z GEMM, m-order matching the
//   NATIVE xc accumulator layout: k-slot (hi=l>>4, i, ks2) -> m = 32*ks2+16*(i>>2)+4*hi+(i&3)
// packW [bn(4)][kk(16)][cf(8)][lane(64)][i(8)] : B-frag for fc GEMM
//   lane l, elem i -> W[bn*128 + cf*16 + (l&15)][kk*32 + (l>>4)*8 + i]
// nc2  [b][m] = -TAU*LOG2E * sum_l bf16(Cb[m][l])^2   (log2-domain bias)
__global__ __launch_bounds__(256) void prep_codebook(
        const float* __restrict__ C, const float* __restrict__ W,
        unsigned short* __restrict__ packA, unsigned short* __restrict__ packB,
        unsigned short* __restrict__ packW, float* __restrict__ nc2) {
    const int gid = blockIdx.x * 256 + threadIdx.x;
    if (gid < 131072) {                       // packA
        const int i  = gid & 7;
        const int l  = (gid >> 3) & 63;
        const int mf = (gid >> 9) & 15;
        const int ks = (gid >> 13) & 1;
        const int b  = gid >> 14;
        const int row = (l & 15) + 16 * mf;                   // m
        const int col = b * 64 + (l >> 4) * 8 + i + 32 * ks;  // feature within C row
        packA[gid] = f2bf(C[(size_t)row * D_IN + col]);
    } else if (gid < 262144) {                // packB (acc-native m-order)
        const int g   = gid - 131072;
        const int i   = g & 7;
        const int l   = (g >> 3) & 63;
        const int n2  = (g >> 9) & 3;
        const int ks2 = (g >> 11) & 7;
        const int b   = g >> 14;
        const int m   = 32 * ks2 + 16 * (i >> 2) + 4 * (l >> 4) + (i & 3);
        const int col = b * 64 + n2 * 16 + (l & 15);
        packB[g] = f2bf(C[(size_t)m * D_IN + col]);
    } else if (gid < 524288) {                // packW
        const int h  = gid - 262144;
        const int i  = h & 7;
        const int l  = (h >> 3) & 63;
        const int cf = (h >> 9) & 7;
        const int kk = (h >> 12) & 15;
        const int bn = h >> 16;
        packW[h] = f2bf(W[(size_t)(bn * 128 + cf * 16 + (l & 15)) * D_IN
                          + kk * 32 + (l >> 4) * 8 + i]);
    } else if (gid < 526336) {                // nc2
        const int t = gid - 524288;
        const int b = t >> 8, m = t & 255;
        const float* cp = C + (size_t)m * D_IN + b * 64;
        float s = 0.f;
        for (int l = 0; l < 64; ++l) {
            const float v = bf2f(f2bf(cp[l]));
            s = fmaf(v, v, s);
        }
        nc2[t] = -TAU * LOG2E * s;
    }
}

// ============ Kernel 1: X = x @ W^T + b  (bf16 MFMA, BM=256, double-buffered) ============
// One barrier per K-step: {issue loads k+1} -> {ds_read + MFMA on buf[cur]} ->
// {vmcnt-wait, cvt, ds_write buf[cur^1]} -> {barrier}.
#define ASTR 40   // x-staging LDS row stride in bf16 elems (80 B)

__global__ __launch_bounds__(512, 4) void gemm_fc(
        const float* __restrict__ x, const unsigned short* __restrict__ packW,
        const float* __restrict__ bias, float* __restrict__ X) {
    __shared__ unsigned short Asm[2][256 * ASTR];                      // 2 x 20 KB
    __shared__ __attribute__((aligned(16))) unsigned short Wsm[2][4096]; // 2 x 8 KB

    const int tid = threadIdx.x;
    const int bid = blockIdx.x;
    // co-XCD grouping: the 4 bn-tiles of one bm sit consecutively on ONE XCD
    const int xcd = bid & 7;
    const int idx = bid >> 3;            // 0..127 per XCD
    const int bm  = xcd * 32 + (idx >> 2);
    const int bn  = idx & 3;
    const int n0 = bm * 256, c0 = bn * 128;
    const int lane = tid & 63, w = tid >> 6;
    const int wr = w >> 1, wc = w & 1;   // wave grid 4 x 2
    const int lo = lane & 15, hi = lane >> 4;

    const int sr = tid >> 1;             // staging row 0..255 (2 threads/row)
    const int sf = (tid & 1) << 4;       // k-offset 0 or 16 floats

    f32x4 acc[4][4];                     // rows wr*64+fm*16+..., cols wc*64+cf*16+lo
    #pragma unroll
    for (int i = 0; i < 4; ++i)
        #pragma unroll
        for (int j = 0; j < 4; ++j) acc[i][j] = (f32x4){0.f, 0.f, 0.f, 0.f};

    const float4* gW = reinterpret_cast<const float4*>(packW);

    // ---- prologue: load + stage K-step 0 into buffer 0 ----
    float4 ra[4];
    float4 rw;
    {
        const float* xa = &x[(size_t)(n0 + sr) * D_IN + sf];
        #pragma unroll
        for (int q = 0; q < 4; ++q)
            ra[q] = *reinterpret_cast<const float4*>(xa + q * 4);
        rw = gW[(size_t)(bn * 16) * 512 + tid];
    }
    #pragma unroll
    for (int q = 0; q < 4; ++q) {
        ushort4 pa;
        pa.x = f2bf(ra[q].x); pa.y = f2bf(ra[q].y);
        pa.z = f2bf(ra[q].z); pa.w = f2bf(ra[q].w);
        *reinterpret_cast<ushort4*>(&Asm[0][sr * ASTR + sf + q * 4]) = pa;
    }
    *reinterpret_cast<float4*>(&Wsm[0][tid * 8]) = rw;
    __syncthreads();

    for (int kk = 0; kk < 16; ++kk) {
        const int cur = kk & 1;
        // issue next step's global loads (completion awaited only after the MFMAs)
        if (kk < 15) {
            const float* xa = &x[(size_t)(n0 + sr) * D_IN + (kk + 1) * 32 + sf];
            #pragma unroll
            for (int q = 0; q < 4; ++q)
                ra[q] = *reinterpret_cast<const float4*>(xa + q * 4);
            rw = gW[(size_t)(bn * 16 + kk + 1) * 512 + tid];
        }
        // compute on buf[cur]
        short8 a[4], bb[4];
        #pragma unroll
        for (int fm = 0; fm < 4; ++fm)
            a[fm] = *reinterpret_cast<const short8*>(
                &Asm[cur][(wr * 64 + fm * 16 + lo) * ASTR + hi * 8]);
        #pragma unroll
        for (int cf = 0; cf < 4; ++cf)
            bb[cf] = *reinterpret_cast<const short8*>(
                &Wsm[cur][((wc * 4 + cf) * 64 + lane) * 8]);
        #pragma unroll
        for (int fm = 0; fm < 4; ++fm)
            #pragma unroll
            for (int cf = 0; cf < 4; ++cf)
                acc[fm][cf] = __builtin_amdgcn_mfma_f32_16x16x32_bf16(
                    a[fm], bb[cf], acc[fm][cf], 0, 0, 0);
        // stage next step into buf[cur^1] (vmcnt wait happens here, after MFMAs)
        if (kk < 15) {
            #pragma unroll
            for (int q = 0; q < 4; ++q) {
                ushort4 pa;
                pa.x = f2bf(ra[q].x); pa.y = f2bf(ra[q].y);
                pa.z = f2bf(ra[q].z); pa.w = f2bf(ra[q].w);
                *reinterpret_cast<ushort4*>(&Asm[cur ^ 1][sr * ASTR + sf + q * 4]) = pa;
            }
            *reinterpret_cast<float4*>(&Wsm[cur ^ 1][tid * 8]) = rw;
            __syncthreads();
        }
    }

    #pragma unroll
    for (int cf = 0; cf < 4; ++cf) {
        const float bv = bias[c0 + wc * 64 + cf * 16 + lo];
        #pragma unroll
        for (int fm = 0; fm < 4; ++fm)
            #pragma unroll
            for (int j = 0; j < 4; ++j)
                X[(size_t)(n0 + wr * 64 + fm * 16 + hi * 4 + j) * D_OUT
                  + c0 + wc * 64 + cf * 16 + lo] = acc[fm][cf][j] + bv;
    }
}

// ============ Kernel 2: soft quantization head — 512 rows/block, X prefetch ============
// Block = (book b, 512 rows), 512 threads; wave w: rows w*64..+63 in 4 x 16-row iters
// vs ALL 256 m. xc = mfma(Cb, X^T): lane (lo,hi) holds p[x-row lo][m=16*mf+4*hi+j].
// Z GEMM's pa built IN-LANE from qa (packB m-order == qa layout). One barrier.
// X loads 1-iter-ahead: vmcnt wait lands after 64 MFMAs. Z stores non-temporal
// (write-once data must not evict x/X from L2/L3).
__global__ __launch_bounds__(512, 4) void quant_head(
        const float* __restrict__ X, const unsigned short* __restrict__ packA,
        const unsigned short* __restrict__ packB, const float* __restrict__ nc2g,
        float* __restrict__ Z) {
    __shared__ __attribute__((aligned(16))) unsigned short cbA[16384];
    __shared__ __attribute__((aligned(16))) unsigned short cbB[16384];
    __shared__ float nc2s[256];

    const int tid  = threadIdx.x;
    const int bid  = blockIdx.x;
    // co-XCD grouping: 8 books of the same 512-row group sit consecutively on ONE XCD
    const int xcd = bid & 7;
    const int idx = bid >> 3;            // 0..127 per XCD
    const int b   = idx & 7;
    const int n0  = (xcd * 16 + (idx >> 3)) * 512;
    const int lane = tid & 63;
    const int w    = tid >> 6;
    const int lo = lane & 15, hi = lane >> 4;
    const int rowbase = n0 + w * 64;     // this wave's 64 rows

    // ---- iter-0 X load first (latency overlaps codebook staging) ----
    float4 rxc[4];
    {
        const float* xp = X + (size_t)(rowbase + lo) * D_OUT + b * 64 + hi * 8;
        rxc[0] = *reinterpret_cast<const float4*>(xp);
        rxc[1] = *reinterpret_cast<const float4*>(xp + 4);
        rxc[2] = *reinterpret_cast<const float4*>(xp + 32);
        rxc[3] = *reinterpret_cast<const float4*>(xp + 36);
    }

    // ---- stage codebook frags + nc2 into LDS ----
    {
        const float4* gA = reinterpret_cast<const float4*>(packA + (size_t)b * 16384);
        const float4* gB = reinterpret_cast<const float4*>(packB + (size_t)b * 16384);
        float4* sA = reinterpret_cast<float4*>(cbA);
        float4* sB = reinterpret_cast<float4*>(cbB);
        #pragma unroll
        for (int it = 0; it < 4; ++it) {
            sA[it * 512 + tid] = gA[it * 512 + tid];
            sB[it * 512 + tid] = gB[it * 512 + tid];
        }
        if (tid < 256) nc2s[tid] = nc2g[b * 256 + tid];
    }
    __syncthreads();   // codebook + nc2 staged

    const float S2 = 2.0f * TAU * LOG2E;
    for (int h = 0; h < 4; ++h) {
        // ---- convert current iter's X to bf16 B-frags ----
        short8 xf0, xf1;
        {
            const float4 v0 = rxc[0], v1 = rxc[1], v2 = rxc[2], v3 = rxc[3];
            xf0[0] = (short)f2bf(v0.x); xf0[1] = (short)f2bf(v0.y);
            xf0[2] = (short)f2bf(v0.z); xf0[3] = (short)f2bf(v0.w);
            xf0[4] = (short)f2bf(v1.x); xf0[5] = (short)f2bf(v1.y);
            xf0[6] = (short)f2bf(v1.z); xf0[7] = (short)f2bf(v1.w);
            xf1[0] = (short)f2bf(v2.x); xf1[1] = (short)f2bf(v2.y);
            xf1[2] = (short)f2bf(v2.z); xf1[3] = (short)f2bf(v2.w);
            xf1[4] = (short)f2bf(v3.x); xf1[5] = (short)f2bf(v3.y);
            xf1[6] = (short)f2bf(v3.z); xf1[7] = (short)f2bf(v3.w);
        }
        // ---- prefetch next iter's X (vmcnt wait lands after this iter's MFMAs) ----
        if (h < 3) {
            const float* xp = X + (size_t)(rowbase + (h + 1) * 16 + lo) * D_OUT + b * 64 + hi * 8;
            rxc[0] = *reinterpret_cast<const float4*>(xp);
            rxc[1] = *reinterpret_cast<const float4*>(xp + 4);
            rxc[2] = *reinterpret_cast<const float4*>(xp + 32);
            rxc[3] = *reinterpret_cast<const float4*>(xp + 36);
        }

        // ---- xc MFMA: 16 rows x 256 m ----
        f32x4 qa[16];
        #pragma unroll
        for (int mf = 0; mf < 16; ++mf) qa[mf] = (f32x4){0.f, 0.f, 0.f, 0.f};
        #pragma unroll
        for (int ks = 0; ks < 2; ++ks)
            #pragma unroll
            for (int mf = 0; mf < 16; ++mf) {
                const short8 cfr = *reinterpret_cast<const short8*>(
                    &cbA[((ks * 16 + mf) * 64 + lane) * 8]);
                qa[mf] = __builtin_amdgcn_mfma_f32_16x16x32_bf16(
                    cfr, ks ? xf1 : xf0, qa[mf], 0, 0, 0);
            }

        // ---- softmax (exp2 domain, in-lane, unnormalized p kept in qa) ----
        float s = 0.f;
        #pragma unroll
        for (int mf = 0; mf < 16; ++mf) {
            const f32x4 nv = *reinterpret_cast<const f32x4*>(&nc2s[mf * 16 + hi * 4]);
            const float p0 = exp2f(fmaf(qa[mf][0], S2, nv[0]));
            const float p1 = exp2f(fmaf(qa[mf][1], S2, nv[1]));
            const float p2 = exp2f(fmaf(qa[mf][2], S2, nv[2]));
            const float p3 = exp2f(fmaf(qa[mf][3], S2, nv[3]));
            qa[mf][0] = p0; qa[mf][1] = p1; qa[mf][2] = p2; qa[mf][3] = p3;
            s += (p0 + p1) + (p2 + p3);
        }
        s += __shfl_xor(s, 16, 64);
        s += __shfl_xor(s, 32, 64);
        const float inv = 1.0f / s;            // full 256-sum for this iter's row `lo`

        // ---- Z = p @ Cb : pa built in-lane (packB m-order == qa layout) ----
        f32x4 acc2[4];
        #pragma unroll
        for (int n2 = 0; n2 < 4; ++n2) acc2[n2] = (f32x4){0.f, 0.f, 0.f, 0.f};
        #pragma unroll
        for (int ks2 = 0; ks2 < 8; ++ks2) {
            short8 pa;
            pa[0] = (short)f2bf(qa[2 * ks2][0]);     pa[1] = (short)f2bf(qa[2 * ks2][1]);
            pa[2] = (short)f2bf(qa[2 * ks2][2]);     pa[3] = (short)f2bf(qa[2 * ks2][3]);
            pa[4] = (short)f2bf(qa[2 * ks2 + 1][0]); pa[5] = (short)f2bf(qa[2 * ks2 + 1][1]);
            pa[6] = (short)f2bf(qa[2 * ks2 + 1][2]); pa[7] = (short)f2bf(qa[2 * ks2 + 1][3]);
            #pragma unroll
            for (int n2 = 0; n2 < 4; ++n2) {
                const short8 bv = *reinterpret_cast<const short8*>(
                    &cbB[((ks2 * 4 + n2) * 64 + lane) * 8]);
                acc2[n2] = __builtin_amdgcn_mfma_f32_16x16x32_bf16(pa, bv, acc2[n2], 0, 0, 0);
            }
        }

        float invr[4];
        #pragma unroll
        for (int j = 0; j < 4; ++j) invr[j] = __shfl(inv, hi * 4 + j, 64);
        #pragma unroll
        for (int n2 = 0; n2 < 4; ++n2)
            #pragma unroll
            for (int j = 0; j < 4; ++j)
                __builtin_nontemporal_store(
                    acc2[n2][j] * invr[j],
                    &Z[(size_t)(rowbase + h * 16 + hi * 4 + j) * D_OUT
                       + b * 64 + n2 * 16 + lo]);
    }
}

// ============ launch ============
extern "C" void kernel_launch(void* const* d_in, const int* in_sizes, int n_in,
                              void* d_out, int out_size, void* d_ws, size_t ws_size,
                              hipStream_t stream) {
    const float* x = (const float*)d_in[0];
    const float* W = (const float*)d_in[1];
    const float* b = (const float*)d_in[2];
    const float* C = (const float*)d_in[3];

    float* X = (float*)d_out;                      // output 0: [65536, 512]
    float* Z = X + (size_t)N_ROWS * D_OUT;         // output 1: [65536, 512]

    unsigned short* packA = (unsigned short*)d_ws;          // 131072 bf16 = 256 KB
    unsigned short* packB = packA + 131072;                 // 131072 bf16 = 256 KB
    unsigned short* packW = packB + 131072;                 // 262144 bf16 = 512 KB
    float*          nc2g  = (float*)(packW + 262144);       // 2048 fp32  =   8 KB

    prep_codebook<<<dim3(2056), dim3(256), 0, stream>>>(C, W, packA, packB, packW, nc2g);
    gemm_fc<<<dim3(1024), dim3(512), 0, stream>>>(x, packW, b, X);
    quant_head<<<dim3(N_BOOKS * (N_ROWS / 512)), dim3(512), 0, stream>>>(
        X, packA, packB, nc2g, Z);
}

// Round 12
// 147.537 us; speedup vs baseline: 4.7088x; 4.7088x over previous
//
#include <hip/hip_runtime.h>
#include <cstdint>
#include <cstddef>

#define N_ROWS   65536
#define D_IN     512
#define D_OUT    512
#define N_WORDS  256
#define N_BOOKS  8
#define TAU      5.0f
#define LOG2E    1.44269504088896340736f

typedef __attribute__((ext_vector_type(8))) short short8;
typedef __attribute__((ext_vector_type(4))) float f32x4;

// hardware bf16 convert (RNE) — native __bf16 lets the compiler pair into v_cvt_pk_bf16_f32
__device__ __forceinline__ unsigned short f2bf(float f) {
    __bf16 h = (__bf16)f;
    return __builtin_bit_cast(unsigned short, h);
}
__device__ __forceinline__ float bf2f(unsigned short h) {
    unsigned u = ((unsigned)h) << 16;
    return __builtin_bit_cast(float, u);
}

// ============ Kernel 0: pre-pack codebook + W into MFMA fragment order ============
// packA [b][ks(2)][mf(16)][lane(64)][i(8)] : A-frag for xc GEMM (row=m, k=feature)
// packB [b][ks2(8)][n2(4)][lane(64)][i(8)] : B-frag for Z GEMM, m-order matching the
//   NATIVE xc accumulator layout: k-slot (hi=l>>4, i, ks2) -> m = 32*ks2+16*(i>>2)+4*hi+(i&3)
// packW [bn(4)][kk(16)][cf(8)][lane(64)][i(8)] : B-frag for fc GEMM
//   lane l, elem i -> W[bn*128 + cf*16 + (l&15)][kk*32 + (l>>4)*8 + i]
// nc2  [b][m] = -TAU*LOG2E * sum_l bf16(Cb[m][l])^2   (log2-domain bias)
__global__ __launch_bounds__(256) void prep_codebook(
        const float* __restrict__ C, const float* __restrict__ W,
        unsigned short* __restrict__ packA, unsigned short* __restrict__ packB,
        unsigned short* __restrict__ packW, float* __restrict__ nc2) {
    const int gid = blockIdx.x * 256 + threadIdx.x;
    if (gid < 131072) {                       // packA
        const int i  = gid & 7;
        const int l  = (gid >> 3) & 63;
        const int mf = (gid >> 9) & 15;
        const int ks = (gid >> 13) & 1;
        const int b  = gid >> 14;
        const int row = (l & 15) + 16 * mf;                   // m
        const int col = b * 64 + (l >> 4) * 8 + i + 32 * ks;  // feature within C row
        packA[gid] = f2bf(C[(size_t)row * D_IN + col]);
    } else if (gid < 262144) {                // packB (acc-native m-order)
        const int g   = gid - 131072;
        const int i   = g & 7;
        const int l   = (g >> 3) & 63;
        const int n2  = (g >> 9) & 3;
        const int ks2 = (g >> 11) & 7;
        const int b   = g >> 14;
        const int m   = 32 * ks2 + 16 * (i >> 2) + 4 * (l >> 4) + (i & 3);
        const int col = b * 64 + n2 * 16 + (l & 15);
        packB[g] = f2bf(C[(size_t)m * D_IN + col]);
    } else if (gid < 524288) {                // packW
        const int h  = gid - 262144;
        const int i  = h & 7;
        const int l  = (h >> 3) & 63;
        const int cf = (h >> 9) & 7;
        const int kk = (h >> 12) & 15;
        const int bn = h >> 16;
        packW[h] = f2bf(W[(size_t)(bn * 128 + cf * 16 + (l & 15)) * D_IN
                          + kk * 32 + (l >> 4) * 8 + i]);
    } else if (gid < 526336) {                // nc2
        const int t = gid - 524288;
        const int b = t >> 8, m = t & 255;
        const float* cp = C + (size_t)m * D_IN + b * 64;
        float s = 0.f;
        for (int l = 0; l < 64; ++l) {
            const float v = bf2f(f2bf(cp[l]));
            s = fmaf(v, v, s);
        }
        nc2[t] = -TAU * LOG2E * s;
    }
}

// ============ Kernel 1: X = x @ W^T + b  (bf16 MFMA, BM=256, double-buffered) ============
// One barrier per K-step: {issue loads k+1} -> {ds_read + MFMA on buf[cur]} ->
// {vmcnt-wait, cvt, ds_write buf[cur^1]} -> {barrier}.
#define ASTR 40   // x-staging LDS row stride in bf16 elems (80 B)

__global__ __launch_bounds__(512, 4) void gemm_fc(
        const float* __restrict__ x, const unsigned short* __restrict__ packW,
        const float* __restrict__ bias, float* __restrict__ X) {
    __shared__ unsigned short Asm[2][256 * ASTR];                      // 2 x 20 KB
    __shared__ __attribute__((aligned(16))) unsigned short Wsm[2][4096]; // 2 x 8 KB

    const int tid = threadIdx.x;
    const int bid = blockIdx.x;
    // co-XCD grouping: the 4 bn-tiles of one bm sit consecutively on ONE XCD
    const int xcd = bid & 7;
    const int idx = bid >> 3;            // 0..127 per XCD
    const int bm  = xcd * 32 + (idx >> 2);
    const int bn  = idx & 3;
    const int n0 = bm * 256, c0 = bn * 128;
    const int lane = tid & 63, w = tid >> 6;
    const int wr = w >> 1, wc = w & 1;   // wave grid 4 x 2
    const int lo = lane & 15, hi = lane >> 4;

    const int sr = tid >> 1;             // staging row 0..255 (2 threads/row)
    const int sf = (tid & 1) << 4;       // k-offset 0 or 16 floats

    f32x4 acc[4][4];                     // rows wr*64+fm*16+..., cols wc*64+cf*16+lo
    #pragma unroll
    for (int i = 0; i < 4; ++i)
        #pragma unroll
        for (int j = 0; j < 4; ++j) acc[i][j] = (f32x4){0.f, 0.f, 0.f, 0.f};

    const float4* gW = reinterpret_cast<const float4*>(packW);

    // ---- prologue: load + stage K-step 0 into buffer 0 ----
    float4 ra[4];
    float4 rw;
    {
        const float* xa = &x[(size_t)(n0 + sr) * D_IN + sf];
        #pragma unroll
        for (int q = 0; q < 4; ++q)
            ra[q] = *reinterpret_cast<const float4*>(xa + q * 4);
        rw = gW[(size_t)(bn * 16) * 512 + tid];
    }
    #pragma unroll
    for (int q = 0; q < 4; ++q) {
        ushort4 pa;
        pa.x = f2bf(ra[q].x); pa.y = f2bf(ra[q].y);
        pa.z = f2bf(ra[q].z); pa.w = f2bf(ra[q].w);
        *reinterpret_cast<ushort4*>(&Asm[0][sr * ASTR + sf + q * 4]) = pa;
    }
    *reinterpret_cast<float4*>(&Wsm[0][tid * 8]) = rw;
    __syncthreads();

    for (int kk = 0; kk < 16; ++kk) {
        const int cur = kk & 1;
        // issue next step's global loads (completion awaited only after the MFMAs)
        if (kk < 15) {
            const float* xa = &x[(size_t)(n0 + sr) * D_IN + (kk + 1) * 32 + sf];
            #pragma unroll
            for (int q = 0; q < 4; ++q)
                ra[q] = *reinterpret_cast<const float4*>(xa + q * 4);
            rw = gW[(size_t)(bn * 16 + kk + 1) * 512 + tid];
        }
        // compute on buf[cur]
        short8 a[4], bb[4];
        #pragma unroll
        for (int fm = 0; fm < 4; ++fm)
            a[fm] = *reinterpret_cast<const short8*>(
                &Asm[cur][(wr * 64 + fm * 16 + lo) * ASTR + hi * 8]);
        #pragma unroll
        for (int cf = 0; cf < 4; ++cf)
            bb[cf] = *reinterpret_cast<const short8*>(
                &Wsm[cur][((wc * 4 + cf) * 64 + lane) * 8]);
        #pragma unroll
        for (int fm = 0; fm < 4; ++fm)
            #pragma unroll
            for (int cf = 0; cf < 4; ++cf)
                acc[fm][cf] = __builtin_amdgcn_mfma_f32_16x16x32_bf16(
                    a[fm], bb[cf], acc[fm][cf], 0, 0, 0);
        // stage next step into buf[cur^1] (vmcnt wait happens here, after MFMAs)
        if (kk < 15) {
            #pragma unroll
            for (int q = 0; q < 4; ++q) {
                ushort4 pa;
                pa.x = f2bf(ra[q].x); pa.y = f2bf(ra[q].y);
                pa.z = f2bf(ra[q].z); pa.w = f2bf(ra[q].w);
                *reinterpret_cast<ushort4*>(&Asm[cur ^ 1][sr * ASTR + sf + q * 4]) = pa;
            }
            *reinterpret_cast<float4*>(&Wsm[cur ^ 1][tid * 8]) = rw;
            __syncthreads();
        }
    }

    #pragma unroll
    for (int cf = 0; cf < 4; ++cf) {
        const float bv = bias[c0 + wc * 64 + cf * 16 + lo];
        #pragma unroll
        for (int fm = 0; fm < 4; ++fm)
            #pragma unroll
            for (int j = 0; j < 4; ++j)
                X[(size_t)(n0 + wr * 64 + fm * 16 + hi * 4 + j) * D_OUT
                  + c0 + wc * 64 + cf * 16 + lo] = acc[fm][cf][j] + bv;
    }
}

// ============ Kernel 2: soft quantization head — 256 rows/block, in-register pa ============
// Block = (book b, 256 rows), 512 threads; wave w: rows w*32..+31 in 2 x 16-row iters
// vs ALL 256 m. xc = mfma(Cb, X^T): lane (lo,hi) holds p[x-row lo][m=16*mf+4*hi+j].
// Z GEMM's pa built IN-LANE from qa (packB m-order == qa layout). One barrier.
// X loads issued upfront and RETIRED into xf before the MFMA region (keeps peak
// live set ~100 VGPR — no spill; r11's loop-carried prefetch spilled qa to scratch).
// Z stores non-temporal: write-once data must not evict x/X from L2/L3.
__global__ __launch_bounds__(512, 4) void quant_head(
        const float* __restrict__ X, const unsigned short* __restrict__ packA,
        const unsigned short* __restrict__ packB, const float* __restrict__ nc2g,
        float* __restrict__ Z) {
    __shared__ __attribute__((aligned(16))) unsigned short cbA[16384];
    __shared__ __attribute__((aligned(16))) unsigned short cbB[16384];
    __shared__ float nc2s[256];

    const int tid  = threadIdx.x;
    const int bid  = blockIdx.x;
    // co-XCD grouping: 8 books of the same row range sit consecutively on ONE XCD
    const int xcd = bid & 7;
    const int idx = bid >> 3;            // 0..255 per XCD
    const int b   = idx & 7;
    const int n0  = (xcd * 32 + (idx >> 3)) * 256;
    const int lane = tid & 63;
    const int w    = tid >> 6;
    const int lo = lane & 15, hi = lane >> 4;

    // ---- X loads for both halves first (HBM latency starts earliest) ----
    float4 rx[2][4];
    #pragma unroll
    for (int h = 0; h < 2; ++h) {
        const float* xp = X + (size_t)(n0 + w * 32 + h * 16 + lo) * D_OUT + b * 64 + hi * 8;
        rx[h][0] = *reinterpret_cast<const float4*>(xp);
        rx[h][1] = *reinterpret_cast<const float4*>(xp + 4);
        rx[h][2] = *reinterpret_cast<const float4*>(xp + 32);
        rx[h][3] = *reinterpret_cast<const float4*>(xp + 36);
    }

    // ---- stage codebook frags + nc2 into LDS ----
    {
        const float4* gA = reinterpret_cast<const float4*>(packA + (size_t)b * 16384);
        const float4* gB = reinterpret_cast<const float4*>(packB + (size_t)b * 16384);
        float4* sA = reinterpret_cast<float4*>(cbA);
        float4* sB = reinterpret_cast<float4*>(cbB);
        #pragma unroll
        for (int it = 0; it < 4; ++it) {
            sA[it * 512 + tid] = gA[it * 512 + tid];
            sB[it * 512 + tid] = gB[it * 512 + tid];
        }
        if (tid < 256) nc2s[tid] = nc2g[b * 256 + tid];
    }

    // ---- convert X to bf16 B-frags while staging lands (retires rx) ----
    short8 xf[2][2];   // [half][ks]
    #pragma unroll
    for (int h = 0; h < 2; ++h)
        #pragma unroll
        for (int ks = 0; ks < 2; ++ks) {
            const float4 v0 = rx[h][ks * 2];
            const float4 v1 = rx[h][ks * 2 + 1];
            short8 t;
            t[0] = (short)f2bf(v0.x); t[1] = (short)f2bf(v0.y);
            t[2] = (short)f2bf(v0.z); t[3] = (short)f2bf(v0.w);
            t[4] = (short)f2bf(v1.x); t[5] = (short)f2bf(v1.y);
            t[6] = (short)f2bf(v1.z); t[7] = (short)f2bf(v1.w);
            xf[h][ks] = t;
        }

    __syncthreads();   // codebook + nc2 staged

    const float S2 = 2.0f * TAU * LOG2E;
    for (int h = 0; h < 2; ++h) {
        // ---- xc MFMA: 16 rows x 256 m ----
        f32x4 qa[16];
        #pragma unroll
        for (int mf = 0; mf < 16; ++mf) qa[mf] = (f32x4){0.f, 0.f, 0.f, 0.f};
        #pragma unroll
        for (int ks = 0; ks < 2; ++ks)
            #pragma unroll
            for (int mf = 0; mf < 16; ++mf) {
                const short8 cfr = *reinterpret_cast<const short8*>(
                    &cbA[((ks * 16 + mf) * 64 + lane) * 8]);
                qa[mf] = __builtin_amdgcn_mfma_f32_16x16x32_bf16(
                    cfr, xf[h][ks], qa[mf], 0, 0, 0);
            }

        // ---- softmax (exp2 domain, in-lane, unnormalized p kept in qa) ----
        float s = 0.f;
        #pragma unroll
        for (int mf = 0; mf < 16; ++mf) {
            const f32x4 nv = *reinterpret_cast<const f32x4*>(&nc2s[mf * 16 + hi * 4]);
            const float p0 = exp2f(fmaf(qa[mf][0], S2, nv[0]));
            const float p1 = exp2f(fmaf(qa[mf][1], S2, nv[1]));
            const float p2 = exp2f(fmaf(qa[mf][2], S2, nv[2]));
            const float p3 = exp2f(fmaf(qa[mf][3], S2, nv[3]));
            qa[mf][0] = p0; qa[mf][1] = p1; qa[mf][2] = p2; qa[mf][3] = p3;
            s += (p0 + p1) + (p2 + p3);
        }
        s += __shfl_xor(s, 16, 64);
        s += __shfl_xor(s, 32, 64);
        const float inv = 1.0f / s;            // full 256-sum for this half's row `lo`

        // ---- Z = p @ Cb : pa built in-lane (packB m-order == qa layout) ----
        f32x4 acc2[4];
        #pragma unroll
        for (int n2 = 0; n2 < 4; ++n2) acc2[n2] = (f32x4){0.f, 0.f, 0.f, 0.f};
        #pragma unroll
        for (int ks2 = 0; ks2 < 8; ++ks2) {
            short8 pa;
            pa[0] = (short)f2bf(qa[2 * ks2][0]);     pa[1] = (short)f2bf(qa[2 * ks2][1]);
            pa[2] = (short)f2bf(qa[2 * ks2][2]);     pa[3] = (short)f2bf(qa[2 * ks2][3]);
            pa[4] = (short)f2bf(qa[2 * ks2 + 1][0]); pa[5] = (short)f2bf(qa[2 * ks2 + 1][1]);
            pa[6] = (short)f2bf(qa[2 * ks2 + 1][2]); pa[7] = (short)f2bf(qa[2 * ks2 + 1][3]);
            #pragma unroll
            for (int n2 = 0; n2 < 4; ++n2) {
                const short8 bv = *reinterpret_cast<const short8*>(
                    &cbB[((ks2 * 4 + n2) * 64 + lane) * 8]);
                acc2[n2] = __builtin_amdgcn_mfma_f32_16x16x32_bf16(pa, bv, acc2[n2], 0, 0, 0);
            }
        }

        float invr[4];
        #pragma unroll
        for (int j = 0; j < 4; ++j) invr[j] = __shfl(inv, hi * 4 + j, 64);
        #pragma unroll
        for (int n2 = 0; n2 < 4; ++n2)
            #pragma unroll
            for (int j = 0; j < 4; ++j)
                __builtin_nontemporal_store(
                    acc2[n2][j] * invr[j],
                    &Z[(size_t)(n0 + w * 32 + h * 16 + hi * 4 + j) * D_OUT
                       + b * 64 + n2 * 16 + lo]);
    }
}

// ============ launch ============
extern "C" void kernel_launch(void* const* d_in, const int* in_sizes, int n_in,
                              void* d_out, int out_size, void* d_ws, size_t ws_size,
                              hipStream_t stream) {
    const float* x = (const float*)d_in[0];
    const float* W = (const float*)d_in[1];
    const float* b = (const float*)d_in[2];
    const float* C = (const float*)d_in[3];

    float* X = (float*)d_out;                      // output 0: [65536, 512]
    float* Z = X + (size_t)N_ROWS * D_OUT;         // output 1: [65536, 512]

    unsigned short* packA = (unsigned short*)d_ws;          // 131072 bf16 = 256 KB
    unsigned short* packB = packA + 131072;                 // 131072 bf16 = 256 KB
    unsigned short* packW = packB + 131072;                 // 262144 bf16 = 512 KB
    float*          nc2g  = (float*)(packW + 262144);       // 2048 fp32  =   8 KB

    prep_codebook<<<dim3(2056), dim3(256), 0, stream>>>(C, W, packA, packB, packW, nc2g);
    gemm_fc<<<dim3(1024), dim3(512), 0, stream>>>(x, packW, b, X);
    quant_head<<<dim3(N_BOOKS * (N_ROWS / 256)), dim3(512), 0, stream>>>(
        X, packA, packB, nc2g, Z);
}